// Round 7
// baseline (340.688 us; speedup 1.0000x reference)
//
#include <hip/hip_runtime.h>
#include <math.h>

#define NR 36
#define NW 32
#define DD 1024
#define EPSF 1e-8f

typedef _Float16 f16x8 __attribute__((ext_vector_type(8)));
typedef float f32x16 __attribute__((ext_vector_type(16)));
#define MFMA32(a, b, c) __builtin_amdgcn_mfma_f32_32x32x16_f16((a), (b), (c), 0, 0, 0)
#define GLD16(srcp, dstp)                                                              \
  __builtin_amdgcn_global_load_lds((const __attribute__((address_space(1))) void*)(srcp), \
                                   (__attribute__((address_space(3))) void*)(dstp), 16, 0, 0)

__device__ __forceinline__ float leakyf(float x) { return x > 0.f ? x : 0.1f * x; }

// ============ split: fp32 -> f16 hi/lo fragment planes, 64B-line reads, coalesced writes ===
// Frag layout (f16): X[((mt*128 + kq)*32 + ml)*8 + j]  (row = mt*32+ml, k = kq*8+j)
// One thread = one row x 16 consecutive k (one 64B line) -> 2 kq chunks per plane.
__global__ __launch_bounds__(256) void split_kernel(
    const float* __restrict__ img, const float* __restrict__ cap,
    _Float16* __restrict__ Ahf, _Float16* __restrict__ Alf,
    _Float16* __restrict__ Bhf, _Float16* __restrict__ Blf) {
  const int t = blockIdx.x * 256 + threadIdx.x;
  const int ATASK = 4608 * 64;   // 144 mt-tiles * 32 rows * 64 kq-pairs
  const int BTASK = 4096 * 64;   // 128 cb * 32 rows * 64 kq-pairs
  const float* src;
  _Float16 *dh, *dl;
  size_t fo;
  if (t < ATASK) {
    const int ml = t & 31;
    const int tmp = t >> 5;
    const int mt = tmp % 144, kq2 = tmp / 144;
    src = img + (size_t)(mt * 32 + ml) * DD + kq2 * 16;
    fo = (((size_t)mt * 128 + kq2 * 2) * 32 + ml) * 8;
    dh = Ahf; dl = Alf;
  } else {
    const int t2 = t - ATASK;
    if (t2 >= BTASK) return;
    const int ml = t2 & 31;
    const int tmp = t2 >> 5;
    const int cb = tmp % 128, kq2 = tmp / 128;
    src = cap + (size_t)(cb * 32 + ml) * DD + kq2 * 16;
    fo = (((size_t)cb * 128 + kq2 * 2) * 32 + ml) * 8;
    dh = Bhf; dl = Blf;
  }
  float a[16];
  *(float4*)&a[0] = *(const float4*)(src);
  *(float4*)&a[4] = *(const float4*)(src + 4);
  *(float4*)&a[8] = *(const float4*)(src + 8);
  *(float4*)&a[12] = *(const float4*)(src + 12);
  f16x8 hv0, lv0, hv1, lv1;
#pragma unroll
  for (int j = 0; j < 8; ++j) {
    const _Float16 h0 = (_Float16)a[j];
    hv0[j] = h0; lv0[j] = (_Float16)(a[j] - (float)h0);
    const _Float16 h1 = (_Float16)a[8 + j];
    hv1[j] = h1; lv1[j] = (_Float16)(a[8 + j] - (float)h1);
  }
  *(f16x8*)(dh + fo) = hv0;
  *(f16x8*)(dh + fo + 256) = hv1;  // next kq: +32*8 halves
  *(f16x8*)(dl + fo) = lv0;
  *(f16x8*)(dl + fo + 256) = lv1;
}

// ============ gram via MFMA: G = Xh Xh^T + Xh Xl^T + Xl Xh^T (3 indep acc chains) =========
// blocks 0..127: image i, waves 0..2 handle tiles (0,0),(0,1),(1,1); mirror-write (0,1).
// blocks 128..255: caption cb, wave 0, single 32x32 tile.
__global__ __launch_bounds__(256) void gram_kernel(
    const _Float16* __restrict__ Ahf, const _Float16* __restrict__ Alf,
    const _Float16* __restrict__ Bhf, const _Float16* __restrict__ Blf,
    float* __restrict__ Gimg, float* __restrict__ Gcap,
    float* __restrict__ imgn, float* __restrict__ capn) {
  const int lane = threadIdx.x & 63;
  const int wv = threadIdx.x >> 6;
  const int lm = lane & 31, kb = lane >> 5;
  if (blockIdx.x < 128) {
    const int i = blockIdx.x;
    if (wv >= 3) return;
    const int mt = (wv == 2) ? 1 : 0;
    const int nt = (wv == 0) ? 0 : 1;
    const int rm = mt * 32 + lm, rn = nt * 32 + lm;
    const bool vm = rm < NR, vn = rn < NR;
    const int gm = i * NR + (vm ? rm : 0), gn = i * NR + (vn ? rn : 0);
    f32x16 acc0 = {}, acc1 = {}, acc2 = {};
    for (int kt = 0; kt < 64; ++kt) {
      const int kq = kt * 2 + kb;
      const size_t om = (((size_t)(gm >> 5) * 128 + kq) * 32 + (gm & 31)) * 8;
      const size_t on = (((size_t)(gn >> 5) * 128 + kq) * 32 + (gn & 31)) * 8;
      const f16x8 z = {};
      const f16x8 ahm = vm ? *(const f16x8*)(Ahf + om) : z;
      const f16x8 alm = vm ? *(const f16x8*)(Alf + om) : z;
      const f16x8 ahn = vn ? *(const f16x8*)(Ahf + on) : z;
      const f16x8 aln = vn ? *(const f16x8*)(Alf + on) : z;
      acc0 = MFMA32(ahm, ahn, acc0);
      acc1 = MFMA32(ahm, aln, acc1);
      acc2 = MFMA32(alm, ahn, acc2);
    }
    float* Gi = Gimg + (size_t)i * NR * NR;
#pragma unroll
    for (int q = 0; q < 16; ++q) {
      const int row32 = (q & 3) + 8 * (q >> 2) + 4 * kb;
      const int m = mt * 32 + row32, n = nt * 32 + lm;
      if (m < NR && n < NR) {
        const float g = acc0[q] + acc1[q] + acc2[q];
        Gi[m * NR + n] = g;
        if (mt != nt) Gi[n * NR + m] = g;
        if (mt == nt && m == n) imgn[i * NR + m] = fmaxf(sqrtf(g), EPSF);
      }
    }
  } else {
    const int cb = blockIdx.x - 128;
    if (wv >= 1) return;
    f32x16 acc0 = {}, acc1 = {}, acc2 = {};
    for (int kt = 0; kt < 64; ++kt) {
      const int kq = kt * 2 + kb;
      const size_t o = (((size_t)cb * 128 + kq) * 32 + lm) * 8;
      const f16x8 bh = *(const f16x8*)(Bhf + o);
      const f16x8 bl = *(const f16x8*)(Blf + o);
      acc0 = MFMA32(bh, bh, acc0);
      acc1 = MFMA32(bh, bl, acc1);
      acc2 = MFMA32(bl, bh, acc2);
    }
    float* Gc = Gcap + (size_t)cb * NW * NW;
#pragma unroll
    for (int q = 0; q < 16; ++q) {
      const int row32 = (q & 3) + 8 * (q >> 2) + 4 * kb;
      const float g = acc0[q] + acc1[q] + acc2[q];
      Gc[row32 * NW + lm] = g;
      if (row32 == lm) capn[cb * NW + row32] = fmaxf(sqrtf(g), EPSF);
    }
  }
}

// ============ MFMA GEMM: B double-buffered in LDS (DMA), A direct global (frag layout) ====
// (unchanged — at the m97-structure plateau, ~850 TF)
__device__ __forceinline__ void gemm_loadA(const _Float16* __restrict__ Ahf,
                                           const _Float16* __restrict__ Alf, int Mt0, int kt,
                                           int kb, int lm, f16x8 ar[2][2][2]) {
#pragma unroll
  for (int mt = 0; mt < 2; ++mt)
#pragma unroll
    for (int ks = 0; ks < 2; ++ks) {
      const size_t o = (((size_t)(Mt0 + mt) * 128) + kt * 4 + ks * 2 + kb) * 256 + lm * 8;
      ar[mt][ks][0] = *(const f16x8*)(Ahf + o);
      ar[mt][ks][1] = *(const f16x8*)(Alf + o);
    }
}

__device__ __forceinline__ void gemm_compute(const _Float16* __restrict__ sb,
                                             const f16x8 ar[2][2][2], f32x16 acc[2][4], int kb,
                                             int lm) {
#pragma unroll
  for (int ks = 0; ks < 2; ++ks) {
#pragma unroll
    for (int nt = 0; nt < 4; ++nt) {
      const int co = (nt * 4 + ks * 2 + kb) * 512 + lm * 8;
      const f16x8 bh = *(const f16x8*)&sb[co];
      const f16x8 bl = *(const f16x8*)&sb[co + 256];
      acc[0][nt] = MFMA32(ar[0][ks][0], bh, acc[0][nt]);
      acc[1][nt] = MFMA32(ar[1][ks][0], bh, acc[1][nt]);
      acc[0][nt] = MFMA32(ar[0][ks][1], bh, acc[0][nt]);
      acc[1][nt] = MFMA32(ar[1][ks][1], bh, acc[1][nt]);
      acc[0][nt] = MFMA32(ar[0][ks][0], bl, acc[0][nt]);
      acc[1][nt] = MFMA32(ar[1][ks][0], bl, acc[1][nt]);
    }
  }
}

__global__ __launch_bounds__(128) void mfma_gemm_kernel(
    const _Float16* __restrict__ Ahf, const _Float16* __restrict__ Alf,
    const _Float16* __restrict__ Bhf, const _Float16* __restrict__ Blf, float* __restrict__ C) {
  __shared__ _Float16 sB[2][8192];
  const int bid = blockIdx.x;
  const int yb = bid & 31, xb = bid >> 5;
  const int n0b = yb * 4;
  const int tid = threadIdx.x;
  const int wv = tid >> 6, lane = tid & 63;
  const int lm = lane & 31, kb = lane >> 5;
  const int Mt0 = xb * 4 + wv * 2;
  const _Float16* Bsrc = kb ? Blf : Bhf;

  auto stageB = [&](int kt, int buf) {
#pragma unroll
    for (int u = 0; u < 8; ++u) {
      const int cp = wv * 8 + u;
      const int nb = cp >> 2, kq = cp & 3;
      const _Float16* src = Bsrc + (((size_t)(n0b + nb) * 128 + kt * 4 + kq) * 32 + lm) * 8;
      GLD16(src, &sB[buf][cp * 512]);
    }
  };

  f32x16 acc[2][4];
#pragma unroll
  for (int a = 0; a < 2; ++a)
#pragma unroll
    for (int b = 0; b < 4; ++b) acc[a][b] = {};
  f16x8 ar0[2][2][2], ar1[2][2][2];

  stageB(0, 0);
  gemm_loadA(Ahf, Alf, Mt0, 0, kb, lm, ar0);
  for (int kt2 = 0; kt2 < 16; ++kt2) {
    const int kt = kt2 * 2;
    __syncthreads();
    if (kt + 1 < 32) {
      stageB(kt + 1, 1);
      gemm_loadA(Ahf, Alf, Mt0, kt + 1, kb, lm, ar1);
    }
    gemm_compute(sB[0], ar0, acc, kb, lm);
    __syncthreads();
    if (kt + 2 < 32) {
      stageB(kt + 2, 0);
      gemm_loadA(Ahf, Alf, Mt0, kt + 2, kb, lm, ar0);
    }
    gemm_compute(sB[1], ar1, acc, kb, lm);
  }
#pragma unroll
  for (int mt = 0; mt < 2; ++mt)
#pragma unroll
    for (int nt = 0; nt < 4; ++nt) {
      const int cc = n0b + nt;
      const f32x16 a = acc[mt][nt];
#pragma unroll
      for (int q = 0; q < 16; ++q) {
        const int row32 = (q & 3) + 8 * (q >> 2) + 4 * kb;
        const int m = (Mt0 + mt) * 32 + row32;
        const int il = m / NR, r = m - il * NR;
        C[((size_t)il * 128 + cc) * (NR * NW) + r * NW + lm] = a[q];
      }
    }
}

// ============ fused post-GEMM: S in LDS (stride 36), G via wave-uniform s_load ============
__global__ __launch_bounds__(256) void fused_attn_kernel(
    const float* __restrict__ C, const float* __restrict__ Gimg, const float* __restrict__ Gcap,
    const float* __restrict__ imgn, const float* __restrict__ capn, float* __restrict__ out) {
  const int i = blockIdx.x;
  const int cg = blockIdx.y;
  const int tid = threadIdx.x;
  const int wv = tid >> 6, lane = tid & 63;
  __shared__ float sS[8][NR * 36];
  __shared__ float sInvR[8][NR];
  __shared__ float sInvC[8][NW];
  __shared__ float red[8];
  if (tid < 8) red[tid] = 0.f;
  const float* Cp = C + ((size_t)i * 128 + cg * 8) * (NR * NW);
  for (int t = tid; t < 8 * NR * NW / 4; t += 256) {
    const int cap = t / (NR * NW / 4);
    const int rem = t - cap * (NR * NW / 4);
    const int r = rem >> 3, wq = rem & 7;
    const float4 v = *(const float4*)(Cp + cap * (NR * NW) + r * NW + wq * 4);
    *(float4*)&sS[cap][r * 36 + wq * 4] = v;
  }
  __syncthreads();
#pragma unroll
  for (int it = 0; it < 2; ++it) {
    const int capu = wv + it * 4;
    if (lane < NR) {
      float rn = 0.f;
#pragma unroll
      for (int k = 0; k < 8; ++k) {
        const float4 v = *(const float4*)&sS[capu][lane * 36 + k * 4];
        float l;
        l = leakyf(v.x); rn = fmaf(l, l, rn);
        l = leakyf(v.y); rn = fmaf(l, l, rn);
        l = leakyf(v.z); rn = fmaf(l, l, rn);
        l = leakyf(v.w); rn = fmaf(l, l, rn);
      }
      sInvR[capu][lane] = 20.f / (sqrtf(rn) + EPSF);
    }
  }
  __syncthreads();
  {
    const int capT = tid >> 5, wT = tid & 31;
    float s[NR], z[NR];
    float cn = 0.f;
#pragma unroll
    for (int j = 0; j < NR; ++j) {
      s[j] = sS[capT][j * 36 + wT];
      const float l = leakyf(s[j]);
      cn = fmaf(l, l, cn);
    }
    sInvC[capT][wT] = 20.f / (sqrtf(cn) + EPSF);
    float mz = -1e30f;
#pragma unroll
    for (int j = 0; j < NR; ++j) {
      z[j] = leakyf(s[j]) * sInvR[capT][j];
      mz = fmaxf(mz, z[j]);
    }
    float s1 = 0.f;
#pragma unroll
    for (int j = 0; j < NR; ++j) { z[j] = __expf(z[j] - mz); s1 += z[j]; }
    const float thr = s1 * (1.f / NR);
    float num = 0.f;
#pragma unroll
    for (int j = 0; j < NR; ++j) {
      z[j] = (z[j] > thr) ? z[j] : 0.f;
      num = fmaf(z[j], s[j], num);
    }
    const float* Gp = Gimg + (size_t)i * (NR * NR);
    float den2 = 0.f;
#pragma unroll
    for (int j = 0; j < NR; ++j) {
      float h = 0.5f * z[j] * Gp[j * NR + j];
#pragma unroll
      for (int j2 = j + 1; j2 < NR; ++j2) h = fmaf(z[j2], Gp[j * NR + j2], h);
      den2 = fmaf(z[j], h, den2);
    }
    const float val = num / (capn[(cg * 8 + capT) * NW + wT] * sqrtf(2.f * den2) + 1e-30f);
    float contrib = val * (1.f / NW);
#pragma unroll
    for (int d = 1; d < 32; d <<= 1) contrib += __shfl_xor(contrib, d, 64);
    if ((tid & 31) == 0) atomicAdd(&red[capT], contrib);
  }
  __syncthreads();
#pragma unroll
  for (int it = 0; it < 2; ++it) {
    const int capu = wv + it * 4;
    const int cglob = cg * 8 + capu;
    float contrib = 0.f;
    if (lane < NR) {
      float sr[NW], z[NW];
#pragma unroll
      for (int k = 0; k < 8; ++k)
        *(float4*)&sr[k * 4] = *(const float4*)&sS[capu][lane * 36 + k * 4];
      float mz = -1e30f;
#pragma unroll
      for (int w = 0; w < NW; ++w) {
        z[w] = leakyf(sr[w]) * sInvC[capu][w];
        mz = fmaxf(mz, z[w]);
      }
      float s1 = 0.f;
#pragma unroll
      for (int w = 0; w < NW; ++w) { z[w] = __expf(z[w] - mz); s1 += z[w]; }
      const float thr = s1 * (1.f / NW);
      float num = 0.f;
#pragma unroll
      for (int w = 0; w < NW; ++w) {
        z[w] = (z[w] > thr) ? z[w] : 0.f;
        num = fmaf(z[w], sr[w], num);
      }
      const float* Gp = Gcap + (size_t)cglob * (NW * NW);
      float den2 = 0.f;
#pragma unroll
      for (int w = 0; w < NW; ++w) {
        float h = 0.5f * z[w] * Gp[w * NW + w];
#pragma unroll
        for (int w2 = w + 1; w2 < NW; ++w2) h = fmaf(z[w2], Gp[w * NW + w2], h);
        den2 = fmaf(z[w], h, den2);
      }
      const float val = num / (imgn[i * NR + lane] * sqrtf(2.f * den2) + 1e-30f);
      contrib = val * (1.f / NR);
    }
#pragma unroll
    for (int d = 1; d < 64; d <<= 1) contrib += __shfl_xor(contrib, d, 64);
    if (lane == 0) atomicAdd(&red[capu], contrib);
  }
  __syncthreads();
  if (tid < 8) out[(size_t)i * 128 + cg * 8 + tid] = red[tid];
}

extern "C" void kernel_launch(void* const* d_in, const int* in_sizes, int n_in,
                              void* d_out, int out_size, void* d_ws, size_t ws_size,
                              hipStream_t stream) {
  (void)in_sizes; (void)n_in; (void)out_size; (void)ws_size;
  const float* images = (const float*)d_in[0];
  const float* captions = (const float*)d_in[1];
  float* out = (float*)d_out;

  char* wb = (char*)d_ws;
  _Float16* Ahf = (_Float16*)wb; wb += (size_t)4608 * 1024 * 2;
  _Float16* Alf = (_Float16*)wb; wb += (size_t)4608 * 1024 * 2;
  _Float16* Bhf = (_Float16*)wb; wb += (size_t)4096 * 1024 * 2;
  _Float16* Blf = (_Float16*)wb; wb += (size_t)4096 * 1024 * 2;
  float* Gimg = (float*)wb; wb += (size_t)128 * NR * NR * 4;
  float* Gcap = (float*)wb; wb += (size_t)128 * NW * NW * 4;
  float* imgn = (float*)wb; wb += (size_t)128 * NR * 4;
  float* capn = (float*)wb; wb += (size_t)128 * NW * 4;
  float* C = (float*)wb;

  split_kernel<<<2176, 256, 0, stream>>>(images, captions, Ahf, Alf, Bhf, Blf);
  gram_kernel<<<256, 256, 0, stream>>>(Ahf, Alf, Bhf, Blf, Gimg, Gcap, imgn, capn);
  mfma_gemm_kernel<<<1152, 128, 0, stream>>>(Ahf, Alf, Bhf, Blf, C);
  fused_attn_kernel<<<dim3(128, 16), 256, 0, stream>>>(C, Gimg, Gcap, imgn, capn, out);
}

// Round 9
// 321.569 us; speedup vs baseline: 1.0595x; 1.0595x over previous
//
#include <hip/hip_runtime.h>
#include <math.h>

#define NR 36
#define NW 32
#define DD 1024
#define EPSF 1e-8f

typedef _Float16 f16x8 __attribute__((ext_vector_type(8)));
typedef float f32x16 __attribute__((ext_vector_type(16)));
#define MFMA32(a, b, c) __builtin_amdgcn_mfma_f32_32x32x16_f16((a), (b), (c), 0, 0, 0)
#define GLD16(srcp, dstp)                                                              \
  __builtin_amdgcn_global_load_lds((const __attribute__((address_space(1))) void*)(srcp), \
                                   (__attribute__((address_space(3))) void*)(dstp), 16, 0, 0)

__device__ __forceinline__ float leakyf(float x) { return x > 0.f ? x : 0.1f * x; }

// ============ prep: grams (full symmetric) + norms + f16 hi/lo fragment planes ============
// blocks 0..127: image i ; blocks 128..255: caption cb
// Frag layout (f16): X[((mt*128 + kq)*32 + ml)*8 + j], row = mt*32+ml, k = kq*8+j
__global__ __launch_bounds__(256) void prep_kernel(
    const float* __restrict__ img, const float* __restrict__ cap,
    float* __restrict__ Gimg, float* __restrict__ Gcap,
    float* __restrict__ imgn, float* __restrict__ capn,
    _Float16* __restrict__ Ahf, _Float16* __restrict__ Alf,
    _Float16* __restrict__ Bhf, _Float16* __restrict__ Blf) {
  __shared__ float sA[NR][68];
  const int t = threadIdx.x;
  if (blockIdx.x < 128) {
    const int i = blockIdx.x;
    const float* A = img + (size_t)i * NR * DD;
    int ti = 0, tj = 0;
    const bool active = t < 171;  // 18*19/2 upper-tri 2x2 tiles
    if (active) {
      int rem = t, rl = 18;
      while (rem >= rl) { rem -= rl; ++ti; --rl; }
      tj = ti + rem;
    }
    const int a0 = 2 * ti, a1 = 2 * ti + 1, b0 = 2 * tj, b1 = 2 * tj + 1;
    float g00 = 0.f, g01 = 0.f, g10 = 0.f, g11 = 0.f;
    for (int k0 = 0; k0 < DD; k0 += 64) {
      for (int s = t; s < NR * 8; s += 256) {  // 288 tasks: kq8 = s/36, r = s%36
        const int kq8 = s / NR, r = s - kq8 * NR;
        const int kk = k0 + kq8 * 8;
        const float4 v0 = *(const float4*)(A + r * DD + kk);
        const float4 v1 = *(const float4*)(A + r * DD + kk + 4);
        *(float4*)&sA[r][kq8 * 8] = v0;
        *(float4*)&sA[r][kq8 * 8 + 4] = v1;
        const float a[8] = {v0.x, v0.y, v0.z, v0.w, v1.x, v1.y, v1.z, v1.w};
        f16x8 hv, lv;
#pragma unroll
        for (int j = 0; j < 8; ++j) {
          const _Float16 hh = (_Float16)a[j];
          hv[j] = hh;
          lv[j] = (_Float16)(a[j] - (float)hh);
        }
        const int m = i * NR + r, mt = m >> 5, ml = m & 31;
        const size_t fo = (((size_t)mt * 128 + (kk >> 3)) * 32 + ml) * 8;
        *(f16x8*)(Ahf + fo) = hv;
        *(f16x8*)(Alf + fo) = lv;
      }
      __syncthreads();
      if (active) {
#pragma unroll
        for (int k = 0; k < 16; ++k) {
          const float4 va0 = *(const float4*)&sA[a0][k * 4];
          const float4 va1 = *(const float4*)&sA[a1][k * 4];
          const float4 vb0 = *(const float4*)&sA[b0][k * 4];
          const float4 vb1 = *(const float4*)&sA[b1][k * 4];
          g00 = fmaf(va0.x, vb0.x, g00); g00 = fmaf(va0.y, vb0.y, g00);
          g00 = fmaf(va0.z, vb0.z, g00); g00 = fmaf(va0.w, vb0.w, g00);
          g01 = fmaf(va0.x, vb1.x, g01); g01 = fmaf(va0.y, vb1.y, g01);
          g01 = fmaf(va0.z, vb1.z, g01); g01 = fmaf(va0.w, vb1.w, g01);
          g10 = fmaf(va1.x, vb0.x, g10); g10 = fmaf(va1.y, vb0.y, g10);
          g10 = fmaf(va1.z, vb0.z, g10); g10 = fmaf(va1.w, vb0.w, g10);
          g11 = fmaf(va1.x, vb1.x, g11); g11 = fmaf(va1.y, vb1.y, g11);
          g11 = fmaf(va1.z, vb1.z, g11); g11 = fmaf(va1.w, vb1.w, g11);
        }
      }
      __syncthreads();
    }
    if (active) {
      float* Gi = Gimg + (size_t)i * NR * NR;
      Gi[a0 * NR + b0] = g00; Gi[b0 * NR + a0] = g00;
      Gi[a0 * NR + b1] = g01; Gi[b1 * NR + a0] = g01;
      Gi[a1 * NR + b0] = g10; Gi[b0 * NR + a1] = g10;
      Gi[a1 * NR + b1] = g11; Gi[b1 * NR + a1] = g11;
      if (ti == tj) {
        imgn[i * NR + a0] = fmaxf(sqrtf(g00), EPSF);
        imgn[i * NR + a1] = fmaxf(sqrtf(g11), EPSF);
      }
    }
  } else {
    const int cb = blockIdx.x - 128;
    const float* A = cap + (size_t)cb * NW * DD;
    int ti = 0, tj = 0;
    const bool active = t < 136;  // 16*17/2
    if (active) {
      int rem = t, rl = 16;
      while (rem >= rl) { rem -= rl; ++ti; --rl; }
      tj = ti + rem;
    }
    const int a0 = 2 * ti, a1 = 2 * ti + 1, b0 = 2 * tj, b1 = 2 * tj + 1;
    float g00 = 0.f, g01 = 0.f, g10 = 0.f, g11 = 0.f;
    for (int k0 = 0; k0 < DD; k0 += 64) {
      {  // 256 tasks: kq8 = s>>5, r = s&31
        const int s = t;
        const int kq8 = s >> 5, r = s & 31;
        const int kk = k0 + kq8 * 8;
        const float4 v0 = *(const float4*)(A + r * DD + kk);
        const float4 v1 = *(const float4*)(A + r * DD + kk + 4);
        *(float4*)&sA[r][kq8 * 8] = v0;
        *(float4*)&sA[r][kq8 * 8 + 4] = v1;
        const float a[8] = {v0.x, v0.y, v0.z, v0.w, v1.x, v1.y, v1.z, v1.w};
        f16x8 hv, lv;
#pragma unroll
        for (int j = 0; j < 8; ++j) {
          const _Float16 hh = (_Float16)a[j];
          hv[j] = hh;
          lv[j] = (_Float16)(a[j] - (float)hh);
        }
        const size_t fo = (((size_t)cb * 128 + (kk >> 3)) * 32 + r) * 8;
        *(f16x8*)(Bhf + fo) = hv;
        *(f16x8*)(Blf + fo) = lv;
      }
      __syncthreads();
      if (active) {
#pragma unroll
        for (int k = 0; k < 16; ++k) {
          const float4 va0 = *(const float4*)&sA[a0][k * 4];
          const float4 va1 = *(const float4*)&sA[a1][k * 4];
          const float4 vb0 = *(const float4*)&sA[b0][k * 4];
          const float4 vb1 = *(const float4*)&sA[b1][k * 4];
          g00 = fmaf(va0.x, vb0.x, g00); g00 = fmaf(va0.y, vb0.y, g00);
          g00 = fmaf(va0.z, vb0.z, g00); g00 = fmaf(va0.w, vb0.w, g00);
          g01 = fmaf(va0.x, vb1.x, g01); g01 = fmaf(va0.y, vb1.y, g01);
          g01 = fmaf(va0.z, vb1.z, g01); g01 = fmaf(va0.w, vb1.w, g01);
          g10 = fmaf(va1.x, vb0.x, g10); g10 = fmaf(va1.y, vb0.y, g10);
          g10 = fmaf(va1.z, vb0.z, g10); g10 = fmaf(va1.w, vb0.w, g10);
          g11 = fmaf(va1.x, vb1.x, g11); g11 = fmaf(va1.y, vb1.y, g11);
          g11 = fmaf(va1.z, vb1.z, g11); g11 = fmaf(va1.w, vb1.w, g11);
        }
      }
      __syncthreads();
    }
    if (active) {
      float* Gc = Gcap + (size_t)cb * NW * NW;
      Gc[a0 * NW + b0] = g00; Gc[b0 * NW + a0] = g00;
      Gc[a0 * NW + b1] = g01; Gc[b1 * NW + a0] = g01;
      Gc[a1 * NW + b0] = g10; Gc[b0 * NW + a1] = g10;
      Gc[a1 * NW + b1] = g11; Gc[b1 * NW + a1] = g11;
      if (ti == tj) {
        capn[cb * NW + a0] = fmaxf(sqrtf(g00), EPSF);
        capn[cb * NW + a1] = fmaxf(sqrtf(g11), EPSF);
      }
    }
  }
}

// ============ MFMA GEMM v2: 256 thr / 4 waves share one B-LDS stage (dbuf DMA) ============
// Block tile 128x128; wave tile 64x64: m-half = wv>>1, n-half = wv&1.
__device__ __forceinline__ void gemm_loadA(const _Float16* __restrict__ Ahf,
                                           const _Float16* __restrict__ Alf, int Mt0, int kt,
                                           int kb, int lm, f16x8 ar[2][2][2]) {
#pragma unroll
  for (int mt = 0; mt < 2; ++mt)
#pragma unroll
    for (int ks = 0; ks < 2; ++ks) {
      const size_t o = (((size_t)(Mt0 + mt) * 128) + kt * 4 + ks * 2 + kb) * 256 + lm * 8;
      ar[mt][ks][0] = *(const f16x8*)(Ahf + o);
      ar[mt][ks][1] = *(const f16x8*)(Alf + o);
    }
}

__global__ __launch_bounds__(256) void mfma_gemm_kernel(
    const _Float16* __restrict__ Ahf, const _Float16* __restrict__ Alf,
    const _Float16* __restrict__ Bhf, const _Float16* __restrict__ Blf, float* __restrict__ C) {
  __shared__ _Float16 sB[2][8192];  // 2 x 16 KB, layout [(nb*4+kq)*512 + plane*256 + lm*8]
  const int bid = blockIdx.x;
  const int yb = bid & 31, xb = bid >> 5;  // grid 1152 = 36 xb * 32 yb
  const int n0b = yb * 4;
  const int tid = threadIdx.x;
  const int wv = tid >> 6, lane = tid & 63;
  const int lm = lane & 31, kb = lane >> 5;
  const int Mt0 = xb * 4 + (wv >> 1) * 2;  // this wave's m-half (2 m-tiles)
  const int nb0 = (wv & 1) * 2;            // this wave's n-half (2 n-tiles)
  const _Float16* Bsrc = kb ? Blf : Bhf;   // half-wave stages its plane (lane ofs = kb*256+lm*8)

  auto stageB = [&](int kt, int buf) {
#pragma unroll
    for (int u = 0; u < 4; ++u) {
      const int cp = wv * 4 + u;  // 0..15 = nb*4 + kq
      const int nb = cp >> 2, kq = cp & 3;
      const _Float16* src = Bsrc + (((size_t)(n0b + nb) * 128 + kt * 4 + kq) * 32 + lm) * 8;
      GLD16(src, &sB[buf][cp * 512]);
    }
  };

  f32x16 acc[2][2];  // [mt][ntl]
#pragma unroll
  for (int a = 0; a < 2; ++a)
#pragma unroll
    for (int b = 0; b < 2; ++b) acc[a][b] = {};
  f16x8 ar0[2][2][2], ar1[2][2][2];

  auto computeBuf = [&](const _Float16* sb, const f16x8 ar[2][2][2]) {
#pragma unroll
    for (int ks = 0; ks < 2; ++ks)
#pragma unroll
      for (int ntl = 0; ntl < 2; ++ntl) {
        const int nt = nb0 + ntl;
        const int co = (nt * 4 + ks * 2 + kb) * 512 + lm * 8;
        const f16x8 bh = *(const f16x8*)&sb[co];
        const f16x8 bl = *(const f16x8*)&sb[co + 256];
        acc[0][ntl] = MFMA32(ar[0][ks][0], bh, acc[0][ntl]);
        acc[1][ntl] = MFMA32(ar[1][ks][0], bh, acc[1][ntl]);
        acc[0][ntl] = MFMA32(ar[0][ks][1], bh, acc[0][ntl]);
        acc[1][ntl] = MFMA32(ar[1][ks][1], bh, acc[1][ntl]);
        acc[0][ntl] = MFMA32(ar[0][ks][0], bl, acc[0][ntl]);
        acc[1][ntl] = MFMA32(ar[1][ks][0], bl, acc[1][ntl]);
      }
  };

  stageB(0, 0);
  gemm_loadA(Ahf, Alf, Mt0, 0, kb, lm, ar0);
  for (int kt2 = 0; kt2 < 16; ++kt2) {
    const int kt = kt2 * 2;
    __syncthreads();  // DMA(kt) + A(kt) landed
    if (kt + 1 < 32) {
      stageB(kt + 1, 1);
      gemm_loadA(Ahf, Alf, Mt0, kt + 1, kb, lm, ar1);
    }
    computeBuf(sB[0], ar0);
    __syncthreads();
    if (kt + 2 < 32) {
      stageB(kt + 2, 0);
      gemm_loadA(Ahf, Alf, Mt0, kt + 2, kb, lm, ar0);
    }
    computeBuf(sB[1], ar1);
  }
  // epilogue: C/D layout col=lane&31, row=(q&3)+8*(q>>2)+4*kb ; C[((il*128+c)*36+r)*32+w]
  // cc = block n-base + wave n-half + local tile  (R8 bug: was n0b + ntl + yb*4)
#pragma unroll
  for (int mt = 0; mt < 2; ++mt)
#pragma unroll
    for (int ntl = 0; ntl < 2; ++ntl) {
      const int cc = n0b + nb0 + ntl;
      const f32x16 a = acc[mt][ntl];
#pragma unroll
      for (int q = 0; q < 16; ++q) {
        const int row32 = (q & 3) + 8 * (q >> 2) + 4 * kb;
        const int m = (Mt0 + mt) * 32 + row32;
        const int il = m / NR, r = m - il * NR;
        C[((size_t)il * 128 + cc) * (NR * NW) + r * NW + lm] = a[q];
      }
    }
}

// ============ fused post-GEMM: S in LDS (stride 36), G via wave-uniform s_load ============
__global__ __launch_bounds__(256) void fused_attn_kernel(
    const float* __restrict__ C, const float* __restrict__ Gimg, const float* __restrict__ Gcap,
    const float* __restrict__ imgn, const float* __restrict__ capn, float* __restrict__ out) {
  const int i = blockIdx.x;
  const int cg = blockIdx.y;
  const int tid = threadIdx.x;
  const int wv = tid >> 6, lane = tid & 63;
  __shared__ float sS[8][NR * 36];
  __shared__ float sInvR[8][NR];
  __shared__ float sInvC[8][NW];
  __shared__ float red[8];
  if (tid < 8) red[tid] = 0.f;
  const float* Cp = C + ((size_t)i * 128 + cg * 8) * (NR * NW);
  for (int t = tid; t < 8 * NR * NW / 4; t += 256) {
    const int cap = t / (NR * NW / 4);
    const int rem = t - cap * (NR * NW / 4);
    const int r = rem >> 3, wq = rem & 7;
    const float4 v = *(const float4*)(Cp + cap * (NR * NW) + r * NW + wq * 4);
    *(float4*)&sS[cap][r * 36 + wq * 4] = v;
  }
  __syncthreads();
#pragma unroll
  for (int it = 0; it < 2; ++it) {
    const int capu = wv + it * 4;
    if (lane < NR) {
      float rn = 0.f;
#pragma unroll
      for (int k = 0; k < 8; ++k) {
        const float4 v = *(const float4*)&sS[capu][lane * 36 + k * 4];
        float l;
        l = leakyf(v.x); rn = fmaf(l, l, rn);
        l = leakyf(v.y); rn = fmaf(l, l, rn);
        l = leakyf(v.z); rn = fmaf(l, l, rn);
        l = leakyf(v.w); rn = fmaf(l, l, rn);
      }
      sInvR[capu][lane] = 20.f / (sqrtf(rn) + EPSF);
    }
  }
  __syncthreads();
  {
    const int capT = tid >> 5, wT = tid & 31;
    float s[NR], z[NR];
    float cn = 0.f;
#pragma unroll
    for (int j = 0; j < NR; ++j) {
      s[j] = sS[capT][j * 36 + wT];
      const float l = leakyf(s[j]);
      cn = fmaf(l, l, cn);
    }
    sInvC[capT][wT] = 20.f / (sqrtf(cn) + EPSF);
    float mz = -1e30f;
#pragma unroll
    for (int j = 0; j < NR; ++j) {
      z[j] = leakyf(s[j]) * sInvR[capT][j];
      mz = fmaxf(mz, z[j]);
    }
    float s1 = 0.f;
#pragma unroll
    for (int j = 0; j < NR; ++j) { z[j] = __expf(z[j] - mz); s1 += z[j]; }
    const float thr = s1 * (1.f / NR);
    float num = 0.f;
#pragma unroll
    for (int j = 0; j < NR; ++j) {
      z[j] = (z[j] > thr) ? z[j] : 0.f;
      num = fmaf(z[j], s[j], num);
    }
    const float* Gp = Gimg + (size_t)i * (NR * NR);
    float den2 = 0.f;
#pragma unroll
    for (int j = 0; j < NR; ++j) {
      float h = 0.5f * z[j] * Gp[j * NR + j];
#pragma unroll
      for (int j2 = j + 1; j2 < NR; ++j2) h = fmaf(z[j2], Gp[j * NR + j2], h);
      den2 = fmaf(z[j], h, den2);
    }
    const float val = num / (capn[(cg * 8 + capT) * NW + wT] * sqrtf(2.f * den2) + 1e-30f);
    float contrib = val * (1.f / NW);
#pragma unroll
    for (int d = 1; d < 32; d <<= 1) contrib += __shfl_xor(contrib, d, 64);
    if ((tid & 31) == 0) atomicAdd(&red[capT], contrib);
  }
  __syncthreads();
#pragma unroll
  for (int it = 0; it < 2; ++it) {
    const int capu = wv + it * 4;
    const int cglob = cg * 8 + capu;
    float contrib = 0.f;
    if (lane < NR) {
      float sr[NW], z[NW];
#pragma unroll
      for (int k = 0; k < 8; ++k)
        *(float4*)&sr[k * 4] = *(const float4*)&sS[capu][lane * 36 + k * 4];
      float mz = -1e30f;
#pragma unroll
      for (int w = 0; w < NW; ++w) {
        z[w] = leakyf(sr[w]) * sInvC[capu][w];
        mz = fmaxf(mz, z[w]);
      }
      float s1 = 0.f;
#pragma unroll
      for (int w = 0; w < NW; ++w) { z[w] = __expf(z[w] - mz); s1 += z[w]; }
      const float thr = s1 * (1.f / NW);
      float num = 0.f;
#pragma unroll
      for (int w = 0; w < NW; ++w) {
        z[w] = (z[w] > thr) ? z[w] : 0.f;
        num = fmaf(z[w], sr[w], num);
      }
      const float* Gp = Gcap + (size_t)cglob * (NW * NW);
      float den2 = 0.f;
#pragma unroll
      for (int w = 0; w < NW; ++w) {
        float h = 0.5f * z[w] * Gp[w * NW + w];
#pragma unroll
        for (int w2 = w + 1; w2 < NW; ++w2) h = fmaf(z[w2], Gp[w * NW + w2], h);
        den2 = fmaf(z[w], h, den2);
      }
      const float val = num / (imgn[i * NR + lane] * sqrtf(2.f * den2) + 1e-30f);
      contrib = val * (1.f / NR);
    }
#pragma unroll
    for (int d = 1; d < 64; d <<= 1) contrib += __shfl_xor(contrib, d, 64);
    if (lane == 0) atomicAdd(&red[capu], contrib);
  }
  __syncthreads();
  if (tid < 8) out[(size_t)i * 128 + cg * 8 + tid] = red[tid];
}

extern "C" void kernel_launch(void* const* d_in, const int* in_sizes, int n_in,
                              void* d_out, int out_size, void* d_ws, size_t ws_size,
                              hipStream_t stream) {
  (void)in_sizes; (void)n_in; (void)out_size; (void)ws_size;
  const float* images = (const float*)d_in[0];
  const float* captions = (const float*)d_in[1];
  float* out = (float*)d_out;

  char* wb = (char*)d_ws;
  _Float16* Ahf = (_Float16*)wb; wb += (size_t)4608 * 1024 * 2;
  _Float16* Alf = (_Float16*)wb; wb += (size_t)4608 * 1024 * 2;
  _Float16* Bhf = (_Float16*)wb; wb += (size_t)4096 * 1024 * 2;
  _Float16* Blf = (_Float16*)wb; wb += (size_t)4096 * 1024 * 2;
  float* Gimg = (float*)wb; wb += (size_t)128 * NR * NR * 4;
  float* Gcap = (float*)wb; wb += (size_t)128 * NW * NW * 4;
  float* imgn = (float*)wb; wb += (size_t)128 * NR * 4;
  float* capn = (float*)wb; wb += (size_t)128 * NW * 4;
  float* C = (float*)wb;

  prep_kernel<<<256, 256, 0, stream>>>(images, captions, Gimg, Gcap, imgn, capn,
                                       Ahf, Alf, Bhf, Blf);
  mfma_gemm_kernel<<<1152, 256, 0, stream>>>(Ahf, Alf, Bhf, Blf, C);
  fused_attn_kernel<<<dim3(128, 16), 256, 0, stream>>>(C, Gimg, Gcap, imgn, capn, out);
}